// Round 16
// baseline (626.167 us; speedup 1.0000x reference)
//
#include <hip/hip_runtime.h>

// LSTM: B=256, T=128, D=64, H=512, 4H=2048, F=256
// Grid: 256 WGs = 16 batch-groups (grp=bid&15) x 16 hidden-slices (slc=bid>>4).
// 4 waves/WG (1/SIMD). Weights in registers (staged via LDS once, r6-proven).
// r16 = r8 protocol + TAGGED h + EARLY FLAG:
//   h element u32 = (f16<<16)|step_tag (4B atomicity pairs tag+value; r7 format).
//   Producer: tagged h store (sc0sc1, no wait) -> RAW s_barrier (no vmcnt drain,
//   unlike __syncthreads) -> tid0 flag store. Flag travels IN PARALLEL with h
//   (removes the producer ack RTT from the serial chain). RAW correctness by
//   tag validation; WAR by flag issue-order (flag(t+1) issued after h(t) loads
//   completed in program order; 2-deep ping-pong as before).
//   Consumer: r8 gate (wave0 polls ONE 64B flag line, sleep-throttled,
//   __syncthreads release) -> issue 8x16B h-loads + obs -> one vmcnt(0) ->
//   tag-validate (retries ~never: h has >=1 RTT head start) -> v_perm strip -> LDS.
// Laws (r3..r15): ONE polling wave/WG, one line/poll; 4-wave WGs; only sc0+sc1
//   rendezvous promptly (r4/r14); atomics==stores at IF$ (r15).

#define WH_S 524   // staging stride (words 262 -> bank hop 6)
#define WX_S 72
#define HT_S 524   // h-tile row stride in f16

typedef __attribute__((ext_vector_type(4))) _Float16 f16x4;
typedef __attribute__((ext_vector_type(4))) float    f32x4;
typedef __attribute__((ext_vector_type(4))) unsigned u32x4;
typedef __attribute__((ext_vector_type(2))) unsigned u32x2;
typedef unsigned long long u64;

__device__ __forceinline__ float sigm(float x)  { return 1.f / (1.f + __expf(-x)); }
__device__ __forceinline__ float tanh_(float x) { float e = __expf(2.f * x); return 1.f - 2.f / (e + 1.f); }

__device__ __forceinline__ u32x4 ldx4_cc(const unsigned* p) {   // IF$-coherent 16B load
    u32x4 v;
    asm volatile("global_load_dwordx4 %0, %1, off sc0 sc1" : "=v"(v) : "v"(p));
    return v;
}
__device__ __forceinline__ void stx4_cc(unsigned* p, u32x4 v) { // IF$-coherent 16B store
    asm volatile("global_store_dwordx4 %0, %1, off sc0 sc1" :: "v"(p), "v"(v) : "memory");
}
__device__ __forceinline__ f32x4 ld128_pl(const void* p) {      // plain cached 16B load
    f32x4 v;
    asm volatile("global_load_dwordx4 %0, %1, off" : "=v"(v) : "v"(p));
    return v;
}
__device__ __forceinline__ unsigned ldflag_cc(const unsigned* p) {  // load + drain
    unsigned v;
    asm volatile("global_load_dword %0, %1, off sc0 sc1\n\ts_waitcnt vmcnt(0)"
                 : "=v"(v) : "v"(p) : "memory");
    return v;
}
__device__ __forceinline__ void stflag_cc(unsigned* p, unsigned v) {
    asm volatile("global_store_dword %0, %1, off sc0 sc1" :: "v"(p), "v"(v) : "memory");
}

#define MFMA16(w, a, c) __builtin_amdgcn_mfma_f32_16x16x16f16((w), (a), (c), 0, 0, 0)

__launch_bounds__(256, 1)
__global__ void lstm_persist(const float* __restrict__ obs,
                             const float* __restrict__ Wx,
                             const float* __restrict__ Wh,
                             const float* __restrict__ bvec,
                             unsigned* __restrict__ hb,     // [2][256][512] u32 (f16<<16|tag)
                             unsigned* __restrict__ flg)    // [16 grp][16 slc] u32 (64B/grp)
{
    __shared__ _Float16 sbuf[128 * WH_S];   // Wh/Wx staging, then h-tile [16][HT_S]

    const int tid = threadIdx.x, lane = tid & 63, wid = tid >> 6;
    const int grp = blockIdx.x & 15, slc = blockIdx.x >> 4;
    const int l15 = lane & 15, l16 = lane >> 4;
    const int c0 = (wid << 5) + l15, c1 = c0 + 16;

    // ---- stage Wh -> LDS -> register frags (mapping HW-verified r4..r8) ----
    for (int idx = tid; idx < 512 * 128; idx += 256) {
        int k = idx >> 7, c = idx & 127;
        int u = ((c >> 5) << 3) | (c & 7);
        int g = (((c >> 4) & 1) << 1) | ((c >> 3) & 1);
        sbuf[c * WH_S + k] = (_Float16)Wh[k * 2048 + (g << 9) + (slc << 5) + u];
    }
    __syncthreads();
    f16x4 wf0[32], wf1[32];
    #pragma unroll
    for (int kk = 0; kk < 32; ++kk) {
        wf0[kk] = *(const f16x4*)&sbuf[c0 * WH_S + (kk << 4) + (l16 << 2)];
        wf1[kk] = *(const f16x4*)&sbuf[c1 * WH_S + (kk << 4) + (l16 << 2)];
    }
    __syncthreads();
    // ---- stage Wx (reuse buffer) -> register frags ----
    for (int idx = tid; idx < 64 * 128; idx += 256) {
        int k = idx >> 7, c = idx & 127;
        int u = ((c >> 5) << 3) | (c & 7);
        int g = (((c >> 4) & 1) << 1) | ((c >> 3) & 1);
        sbuf[c * WX_S + k] = (_Float16)Wx[k * 2048 + (g << 9) + (slc << 5) + u];
    }
    __syncthreads();
    f16x4 xw0[4], xw1[4];
    #pragma unroll
    for (int kx = 0; kx < 4; ++kx) {
        xw0[kx] = *(const f16x4*)&sbuf[c0 * WX_S + (kx << 4) + (l16 << 2)];
        xw1[kx] = *(const f16x4*)&sbuf[c1 * WX_S + (kx << 4) + (l16 << 2)];
    }
    __syncthreads();
    _Float16* const sh = sbuf;                         // h-tile [16][HT_S] from here on

    const int brow = (grp << 4) + l15;                 // B-frag batch row
    const int ub   = (wid << 3) + ((l16 & 1) << 2);
    f32x4 bia[4];
    #pragma unroll
    for (int g = 0; g < 4; ++g)
        bia[g] = *(const f32x4*)(bvec + (g << 9) + (slc << 5) + ub);

    const int r_ld = (wid << 2) + l16;                 // row this lane stages (0..15)
    const int ch16 = l15;                              // chunk index within row
    const int rowg = (grp << 4) + r_ld;                // global batch row staged
    const int hst  = (brow << 9) + (slc << 5) + (wid << 3) + ((l16 & 1) << 2);  // u32 idx
    unsigned* const gflg = flg + (grp << 4);

    float c_reg[4] = {0.f, 0.f, 0.f, 0.f};

    for (int t = 0; t < 128; ++t) {
        // ---- gate: wave0 polls the group's 16 flags (one 64B line) ----
        if (t) {
            if (wid == 0) {
                const unsigned tgt = (unsigned)t;
                for (;;) {
                    unsigned f = ldflag_cc(gflg + l15);
                    if (__all((int)(f >= tgt))) break;
                    __builtin_amdgcn_s_sleep(1);
                }
            }
            __syncthreads();       // release; also orders LDS WAR (reads(t-1) done)
        }

        // ---- issue h(t) tagged loads (critical path) + obs loads, one drain ----
        const unsigned* src = hb + ((t & 1) ? 131072 : 0) + (rowg << 9) + (ch16 << 2);
        u32x4 v[8];
        #pragma unroll
        for (int j = 0; j < 8; ++j) v[j] = ldx4_cc(src + (j << 6));
        f32x4 ov[4];
        const float* op = obs + ((brow << 7) + t) * 64;
        #pragma unroll
        for (int kx = 0; kx < 4; ++kx) ov[kx] = ld128_pl(op + (kx << 4) + (l16 << 2));

        // ---- validate tags, re-issue stale chunks (expected: zero retries) ----
        {
            const unsigned tagt = (unsigned)t;
            unsigned pend = 0xffu;
            for (;;) {
                asm volatile("s_waitcnt vmcnt(0)" ::: "memory");
                unsigned np = 0;
                #pragma unroll
                for (int j = 0; j < 8; ++j) {
                    if (pend & (1u << j)) {
                        bool ok = ((v[j][0] & 0xffffu) == tagt) & ((v[j][1] & 0xffffu) == tagt)
                                & ((v[j][2] & 0xffffu) == tagt) & ((v[j][3] & 0xffffu) == tagt);
                        if (!ok) { np |= (1u << j); v[j] = ldx4_cc(src + (j << 6)); }
                    }
                }
                pend = np;
                if (!__any((int)pend)) break;
            }
        }

        // ---- cvt obs (landed under the h RTT) ----
        f16x4 xf[4];
        #pragma unroll
        for (int kx = 0; kx < 4; ++kx) {
            #pragma unroll
            for (int e = 0; e < 4; ++e) xf[kx][e] = (_Float16)ov[kx][e];
        }

        // ---- strip tags, write LDS tile ----
        #pragma unroll
        for (int j = 0; j < 8; ++j) {
            u32x2 wv;
            wv[0] = __builtin_amdgcn_perm(v[j][1], v[j][0], 0x07060302);
            wv[1] = __builtin_amdgcn_perm(v[j][3], v[j][2], 0x07060302);
            *(u32x2*)&sh[r_ld * HT_S + (j << 6) + (ch16 << 2)] = wv;
        }
        __syncthreads();

        f32x4 a00 = {0.f,0.f,0.f,0.f}, a01 = {0.f,0.f,0.f,0.f};
        f32x4 a10 = {0.f,0.f,0.f,0.f}, a11 = {0.f,0.f,0.f,0.f};
        #pragma unroll
        for (int kx = 0; kx < 4; ++kx) {
            if (kx & 1) { a01 = MFMA16(xw0[kx], xf[kx], a01); a11 = MFMA16(xw1[kx], xf[kx], a11); }
            else        { a00 = MFMA16(xw0[kx], xf[kx], a00); a10 = MFMA16(xw1[kx], xf[kx], a10); }
        }
        #pragma unroll
        for (int kk = 0; kk < 32; ++kk) {
            f16x4 af = *(const f16x4*)&sh[l15 * HT_S + (kk << 4) + (l16 << 2)];
            if (kk & 1) { a01 = MFMA16(wf0[kk], af, a01); a11 = MFMA16(wf1[kk], af, a11); }
            else        { a00 = MFMA16(wf0[kk], af, a00); a10 = MFMA16(wf1[kk], af, a10); }
        }
        f32x4 t0 = a00 + a01, t1 = a10 + a11;   // t0: gate l16>>1; t1: gate 2+(l16>>1)

        // pair exchange lane <-> lane^32: same units, complementary gates (r5-verified)
        f32x4 r0, r1;
        #pragma unroll
        for (int rr = 0; rr < 4; ++rr) {
            r0[rr] = __shfl_xor(t0[rr], 32, 64);
            r1[rr] = __shfl_xor(t1[rr], 32, 64);
        }
        const bool low = (l16 < 2);
        f16x4 hv;
        #pragma unroll
        for (int rr = 0; rr < 4; ++rr) {
            float I  = low ? t0[rr] : r0[rr];
            float Fv = low ? r0[rr] : t0[rr];
            float G  = low ? t1[rr] : r1[rr];
            float O  = low ? r1[rr] : t1[rr];
            I  = sigm (I  + bia[0][rr]);
            Fv = sigm (Fv + bia[1][rr]);
            G  = tanh_(G  + bia[2][rr]);
            O  = sigm (O  + bia[3][rr]);
            float cn  = Fv * c_reg[rr] + I * G;
            c_reg[rr] = cn;
            hv[rr] = (_Float16)(O * tanh_(cn));
        }
        if (low) {                               // tagged h store: fire and forget
            unsigned* dst = hb + (((t + 1) & 1) ? 131072 : 0) + hst;
            u32x4 st;
            #pragma unroll
            for (int rr = 0; rr < 4; ++rr) {
                unsigned short hbits = __builtin_bit_cast(unsigned short, (_Float16)hv[rr]);
                st[rr] = (unsigned)(t + 1) | ((unsigned)hbits << 16);
            }
            stx4_cc(dst, st);
        }

        if (t < 127) {                           // EARLY publish: raw barrier, NO drain
            __builtin_amdgcn_s_barrier();        // all 4 waves ISSUED their h stores
            if (tid == 0)
                stflag_cc(gflg + slc, (unsigned)(t + 1));
        }
    }
}

__launch_bounds__(256)
__global__ void final_proj(const unsigned* __restrict__ hlast,  // [256][512] u32, val=hi16
                           const float* __restrict__ Wd,        // [512][256]
                           const float* __restrict__ bd,        // [256]
                           float* __restrict__ out)             // [256][256]
{
    __shared__ float shm[2048];
    const int tid = threadIdx.x;
    const int rb  = blockIdx.x;
    for (int idx = tid; idx < 2048; idx += 256) {
        unsigned r = hlast[(rb << 2) * 512 + idx];
        shm[idx] = (float)__builtin_bit_cast(_Float16, (unsigned short)(r >> 16));
    }
    __syncthreads();
    float a0 = 0.f, a1 = 0.f, a2 = 0.f, a3 = 0.f;
    for (int k = 0; k < 512; ++k) {
        float w = Wd[(k << 8) + tid];
        a0 += shm[k] * w; a1 += shm[512 + k] * w; a2 += shm[1024 + k] * w; a3 += shm[1536 + k] * w;
    }
    float bb = bd[tid];
    float v0 = a0 + bb, v1 = a1 + bb, v2 = a2 + bb, v3 = a3 + bb;
    out[((rb << 2) + 0) * 256 + tid] = v0 > 0.f ? v0 : 0.f;
    out[((rb << 2) + 1) * 256 + tid] = v1 > 0.f ? v1 : 0.f;
    out[((rb << 2) + 2) * 256 + tid] = v2 > 0.f ? v2 : 0.f;
    out[((rb << 2) + 3) * 256 + tid] = v3 > 0.f ? v3 : 0.f;
}

extern "C" void kernel_launch(void* const* d_in, const int* in_sizes, int n_in,
                              void* d_out, int out_size, void* d_ws, size_t ws_size,
                              hipStream_t stream)
{
    (void)in_sizes; (void)n_in; (void)out_size; (void)ws_size;
    const float* obs = (const float*)d_in[0];
    const float* Wx  = (const float*)d_in[1];
    const float* Wh  = (const float*)d_in[2];
    const float* bv  = (const float*)d_in[3];
    const float* Wd  = (const float*)d_in[4];
    const float* bd  = (const float*)d_in[5];
    float* out = (float*)d_out;

    unsigned* hb  = (unsigned*)d_ws;                           // 2*256*512*4 = 1 MiB
    unsigned* flg = (unsigned*)((char*)d_ws + 1048576);        // 16 grp x 16 u32 = 1024 B

    (void)hipMemsetAsync(d_ws, 0, 1048576 + 1024, stream);     // tags=0 == h0=0 (replay-safe)

    void* args[6];
    args[0] = (void*)&obs; args[1] = (void*)&Wx; args[2] = (void*)&Wh;
    args[3] = (void*)&bv;  args[4] = (void*)&hb; args[5] = (void*)&flg;
    hipError_t e = hipLaunchCooperativeKernel((const void*)lstm_persist,
                                              dim3(256), dim3(256), args, 0, stream);
    if (e != hipSuccess) {
        // 256 WGs x 1 WG/CU (LDS-limited) co-reside on 256 CUs; plain launch is safe.
        lstm_persist<<<dim3(256), dim3(256), 0, stream>>>(obs, Wx, Wh, bv, hb, flg);
    }
    final_proj<<<dim3(64), dim3(256), 0, stream>>>(hb, Wd, bd, out);
}

// Round 19
// 516.815 us; speedup vs baseline: 1.2116x; 1.2116x over previous
//
#include <hip/hip_runtime.h>

// LSTM: B=256, T=128, D=64, H=512, 4H=2048, F=256
// Grid: 256 WGs = 16 batch-groups (grp=bid&15) x 16 hidden-slices (slc=bid>>4).
// 4 waves/WG (1/SIMD). Weights in registers (staged via LDS once, r6-proven).
// r19 = r18 + the rule-#18 fence: sched_barrier(0) after the shared vmcnt(0)
//   drain. r18's failure: obs cvt (register-only) was HOISTED above the
//   inline-asm vmcnt(0) ("memory" clobber orders memory ops, not reg-only
//   VALU) -> cvt read in-flight load destinations. LDS h-writes were safe
//   (memory ops) which is why r15 passed with the same drain pattern.
// Protocol (r8-proven, 545.9us): wave0-only sleep-throttled poll of the
//   group's 16 flags in ONE 64B line; producer vmcnt(0) -> __syncthreads ->
//   tid0 single flag publish (return-less atomic == store, r15).
// Laws (r3..r18): one poller/WG, one line/poll; drain-then-flag; flags!=data;
//   4-wave WGs; sc0+sc1 (IF$) only (r4/r14); atomics==stores (r15); tags cost
//   > ack gain (r16); reg-only consumers of asm loads need sched_barrier (r18).

#define WH_S 524   // staging stride (words 262 -> bank hop 6)
#define WX_S 72
#define HT_S 524   // h-tile row stride in f16

typedef __attribute__((ext_vector_type(4))) _Float16 f16x4;
typedef __attribute__((ext_vector_type(4))) float    f32x4;
typedef __attribute__((ext_vector_type(2))) unsigned long long u64x2;
typedef unsigned long long u64;

__device__ __forceinline__ float sigm(float x)  { return 1.f / (1.f + __expf(-x)); }
__device__ __forceinline__ float tanh_(float x) { float e = __expf(2.f * x); return 1.f - 2.f / (e + 1.f); }

__device__ __forceinline__ u64x2 ld128_cc(const void* p) {   // IF$-coherent 16B load (no wait)
    u64x2 v;
    asm volatile("global_load_dwordx4 %0, %1, off sc0 sc1" : "=v"(v) : "v"(p));
    return v;
}
__device__ __forceinline__ f32x4 ld128_pl(const void* p) {   // plain cached 16B load (no wait)
    f32x4 v;
    asm volatile("global_load_dwordx4 %0, %1, off" : "=v"(v) : "v"(p));
    return v;
}
__device__ __forceinline__ unsigned ldflag_cc(const unsigned* p) {  // load + drain (valid)
    unsigned v;
    asm volatile("global_load_dword %0, %1, off sc0 sc1\n\ts_waitcnt vmcnt(0)"
                 : "=v"(v) : "v"(p) : "memory");
    return v;
}
// return-less atomics: execute at the IF$ (device scope); == stores per r15
__device__ __forceinline__ void at_st64(u64* p, u64 v) {
    asm volatile("global_atomic_swap_x2 %0, %1, off sc1" :: "v"(p), "v"(v) : "memory");
}
__device__ __forceinline__ void at_stflag(unsigned* p, unsigned v) {
    asm volatile("global_atomic_swap %0, %1, off sc1" :: "v"(p), "v"(v) : "memory");
}

#define MFMA16(w, a, c) __builtin_amdgcn_mfma_f32_16x16x16f16((w), (a), (c), 0, 0, 0)

__launch_bounds__(256, 1)
__global__ void lstm_persist(const float* __restrict__ obs,
                             const float* __restrict__ Wx,
                             const float* __restrict__ Wh,
                             const float* __restrict__ bvec,
                             u64* __restrict__ hbuf,        // [2][256][512] f16 as u64
                             unsigned* __restrict__ flg)    // [16 grp][16 slc] u32 (64B/grp)
{
    __shared__ _Float16 sbuf[128 * WH_S];   // Wh/Wx staging, then h-tile [16][HT_S]

    const int tid = threadIdx.x, lane = tid & 63, wid = tid >> 6;
    const int grp = blockIdx.x & 15, slc = blockIdx.x >> 4;
    const int l15 = lane & 15, l16 = lane >> 4;
    const int c0 = (wid << 5) + l15, c1 = c0 + 16;

    // ---- stage Wh -> LDS -> register frags (mapping HW-verified r4..r8) ----
    for (int idx = tid; idx < 512 * 128; idx += 256) {
        int k = idx >> 7, c = idx & 127;
        int u = ((c >> 5) << 3) | (c & 7);
        int g = (((c >> 4) & 1) << 1) | ((c >> 3) & 1);
        sbuf[c * WH_S + k] = (_Float16)Wh[k * 2048 + (g << 9) + (slc << 5) + u];
    }
    __syncthreads();
    f16x4 wf0[32], wf1[32];
    #pragma unroll
    for (int kk = 0; kk < 32; ++kk) {
        wf0[kk] = *(const f16x4*)&sbuf[c0 * WH_S + (kk << 4) + (l16 << 2)];
        wf1[kk] = *(const f16x4*)&sbuf[c1 * WH_S + (kk << 4) + (l16 << 2)];
    }
    __syncthreads();
    // ---- stage Wx (reuse buffer) -> register frags ----
    for (int idx = tid; idx < 64 * 128; idx += 256) {
        int k = idx >> 7, c = idx & 127;
        int u = ((c >> 5) << 3) | (c & 7);
        int g = (((c >> 4) & 1) << 1) | ((c >> 3) & 1);
        sbuf[c * WX_S + k] = (_Float16)Wx[k * 2048 + (g << 9) + (slc << 5) + u];
    }
    __syncthreads();
    f16x4 xw0[4], xw1[4];
    #pragma unroll
    for (int kx = 0; kx < 4; ++kx) {
        xw0[kx] = *(const f16x4*)&sbuf[c0 * WX_S + (kx << 4) + (l16 << 2)];
        xw1[kx] = *(const f16x4*)&sbuf[c1 * WX_S + (kx << 4) + (l16 << 2)];
    }
    __syncthreads();
    _Float16* const sh = sbuf;                         // h-tile [16][HT_S] from here on

    const int brow = (grp << 4) + l15;                 // B-frag batch row
    const int ub   = (wid << 3) + ((l16 & 1) << 2);
    f32x4 bia[4];
    #pragma unroll
    for (int g = 0; g < 4; ++g)
        bia[g] = *(const f32x4*)(bvec + (g << 9) + (slc << 5) + ub);

    const int r_ld  = (wid << 2) + l16;                // row this lane stages (0..15)
    const int ch16  = l15;                             // 16B-chunk index
    const int hstore_idx = (brow << 7) + (slc << 3) + (wid << 1) + (l16 & 1);
    unsigned* const gflg = flg + (grp << 4);

    float c_reg[4] = {0.f, 0.f, 0.f, 0.f};

    for (int t = 0; t < 128; ++t) {
        const u64* hc = hbuf + ((t & 1) ? 32768 : 0);
        u64*       hn = hbuf + ((t & 1) ? 0 : 32768);

        // ---- issue obs loads (no wait): latency hides under the poll ----
        f32x4 ov[4];
        const float* op = obs + ((brow << 7) + t) * 64;
        #pragma unroll
        for (int kx = 0; kx < 4; ++kx) ov[kx] = ld128_pl(op + (kx << 4) + (l16 << 2));
        __builtin_amdgcn_sched_barrier(0);

        // ---- wait for all 16 producers of h(t): one 64B coalesced poll (wave0) ----
        if (t) {
            if (wid == 0) {
                const unsigned tgt = (unsigned)t;
                for (;;) {
                    unsigned f = ldflag_cc(gflg + l15);      // 64 lanes, one line
                    if (__all((int)(f >= tgt))) break;
                    __builtin_amdgcn_s_sleep(1);
                }
            }
            __syncthreads();
        }

        // ---- cooperative h(t) broadcast: 4 coalesced 16B sc0sc1 loads/wave ----
        const u64* hrow = hc + (((grp << 4) + r_ld) << 7) + (ch16 << 1);
        u64x2 hv4[4];
        #pragma unroll
        for (int j = 0; j < 4; ++j) hv4[j] = ld128_cc(hrow + (j << 5));
        asm volatile("s_waitcnt vmcnt(0)" ::: "memory");     // drains h + obs together
        __builtin_amdgcn_sched_barrier(0);                   // rule #18: pin reg-only uses
        #pragma unroll
        for (int j = 0; j < 4; ++j) {                        // LDS tile write (8B-aligned)
            *(u64*)&sh[r_ld * HT_S + (j << 7) + (ch16 << 3)]     = hv4[j][0];
            *(u64*)&sh[r_ld * HT_S + (j << 7) + (ch16 << 3) + 4] = hv4[j][1];
        }
        // ---- cvt obs (landed; fenced behind the drain by sched_barrier) ----
        f16x4 xf[4];
        #pragma unroll
        for (int kx = 0; kx < 4; ++kx) {
            #pragma unroll
            for (int e = 0; e < 4; ++e) xf[kx][e] = (_Float16)ov[kx][e];
        }
        __syncthreads();

        f32x4 a00 = {0.f,0.f,0.f,0.f}, a01 = {0.f,0.f,0.f,0.f};
        f32x4 a10 = {0.f,0.f,0.f,0.f}, a11 = {0.f,0.f,0.f,0.f};

        // Wx MFMAs first (pure-reg) while af ds_reads stream in
        #pragma unroll
        for (int kx = 0; kx < 4; ++kx) {
            if (kx & 1) { a01 = MFMA16(xw0[kx], xf[kx], a01); a11 = MFMA16(xw1[kx], xf[kx], a11); }
            else        { a00 = MFMA16(xw0[kx], xf[kx], a00); a10 = MFMA16(xw1[kx], xf[kx], a10); }
        }
        #pragma unroll
        for (int kk = 0; kk < 32; ++kk) {
            f16x4 af = *(const f16x4*)&sh[l15 * HT_S + (kk << 4) + (l16 << 2)];
            if (kk & 1) { a01 = MFMA16(wf0[kk], af, a01); a11 = MFMA16(wf1[kk], af, a11); }
            else        { a00 = MFMA16(wf0[kk], af, a00); a10 = MFMA16(wf1[kk], af, a10); }
        }
        f32x4 t0 = a00 + a01, t1 = a10 + a11;   // t0: gate l16>>1; t1: gate 2+(l16>>1)

        // pair exchange lane <-> lane^32: same units, complementary gates (r5-verified)
        f32x4 r0, r1;
        #pragma unroll
        for (int rr = 0; rr < 4; ++rr) {
            r0[rr] = __shfl_xor(t0[rr], 32, 64);
            r1[rr] = __shfl_xor(t1[rr], 32, 64);
        }
        const bool low = (l16 < 2);
        f16x4 hv;
        #pragma unroll
        for (int rr = 0; rr < 4; ++rr) {
            float I  = low ? t0[rr] : r0[rr];
            float Fv = low ? r0[rr] : t0[rr];
            float G  = low ? t1[rr] : r1[rr];
            float O  = low ? r1[rr] : t1[rr];
            I  = sigm (I  + bia[0][rr]);
            Fv = sigm (Fv + bia[1][rr]);
            G  = tanh_(G  + bia[2][rr]);
            O  = sigm (O  + bia[3][rr]);
            float cn  = Fv * c_reg[rr] + I * G;
            c_reg[rr] = cn;
            hv[rr] = (_Float16)(O * tanh_(cn));
        }
        if (low)                                 // publish h via IF$-executing atomic
            at_st64(hn + hstore_idx, __builtin_bit_cast(u64, hv));

        if (t < 127) {                           // publish: ack atomics, ONE flag atomic
            asm volatile("s_waitcnt vmcnt(0)" ::: "memory");   // only h outstanding here
            __syncthreads();                                   // all 4 waves acked
            if (tid == 0)
                at_stflag(gflg + slc, (unsigned)(t + 1));
        }
    }
}

__launch_bounds__(256)
__global__ void final_proj(const _Float16* __restrict__ hlast,  // [256][512] f16 (hbuf[0])
                           const float* __restrict__ Wd,        // [512][256]
                           const float* __restrict__ bd,        // [256]
                           float* __restrict__ out)             // [256][256]
{
    __shared__ float shm[2048];
    const int tid = threadIdx.x;
    const int rb  = blockIdx.x;
    for (int idx = tid; idx < 2048; idx += 256)
        shm[idx] = (float)hlast[(rb << 2) * 512 + idx];
    __syncthreads();
    float a0 = 0.f, a1 = 0.f, a2 = 0.f, a3 = 0.f;
    for (int k = 0; k < 512; ++k) {
        float w = Wd[(k << 8) + tid];
        a0 += shm[k] * w; a1 += shm[512 + k] * w; a2 += shm[1024 + k] * w; a3 += shm[1536 + k] * w;
    }
    float bb = bd[tid];
    float v0 = a0 + bb, v1 = a1 + bb, v2 = a2 + bb, v3 = a3 + bb;
    out[((rb << 2) + 0) * 256 + tid] = v0 > 0.f ? v0 : 0.f;
    out[((rb << 2) + 1) * 256 + tid] = v1 > 0.f ? v1 : 0.f;
    out[((rb << 2) + 2) * 256 + tid] = v2 > 0.f ? v2 : 0.f;
    out[((rb << 2) + 3) * 256 + tid] = v3 > 0.f ? v3 : 0.f;
}

extern "C" void kernel_launch(void* const* d_in, const int* in_sizes, int n_in,
                              void* d_out, int out_size, void* d_ws, size_t ws_size,
                              hipStream_t stream)
{
    (void)in_sizes; (void)n_in; (void)out_size; (void)ws_size;
    const float* obs = (const float*)d_in[0];
    const float* Wx  = (const float*)d_in[1];
    const float* Wh  = (const float*)d_in[2];
    const float* bv  = (const float*)d_in[3];
    const float* Wd  = (const float*)d_in[4];
    const float* bd  = (const float*)d_in[5];
    float* out = (float*)d_out;

    u64* hbuf     = (u64*)d_ws;                                // 2*256*512*2 = 524288 B
    unsigned* flg = (unsigned*)((char*)d_ws + 524288);         // 16 grp x 16 u32 = 1024 B

    (void)hipMemsetAsync(d_ws, 0, 524288 + 1024, stream);      // zero h0 + flags

    void* args[6];
    args[0] = (void*)&obs; args[1] = (void*)&Wx; args[2] = (void*)&Wh;
    args[3] = (void*)&bv;  args[4] = (void*)&hbuf; args[5] = (void*)&flg;
    hipError_t e = hipLaunchCooperativeKernel((const void*)lstm_persist,
                                              dim3(256), dim3(256), args, 0, stream);
    if (e != hipSuccess) {
        // 256 WGs x 1 WG/CU (LDS-limited) co-reside on 256 CUs; plain launch is safe.
        lstm_persist<<<dim3(256), dim3(256), 0, stream>>>(obs, Wx, Wh, bv, hbuf, flg);
    }
    final_proj<<<dim3(64), dim3(256), 0, stream>>>((const _Float16*)d_ws, Wd, bd, out);
}